// Round 5
// baseline (463.235 us; speedup 1.0000x reference)
//
#include <hip/hip_runtime.h>

// MergeAdapter: out = x + Up_n(relu(Down_n(x))), merged expert weights.
// N=16, S=2048, H=1024, Kexp=8, D=256. fp32 in/out, bf16 MFMA internally.
//
// Round 7: TLP x pipeline. R5 (2 blk/CU, drain-0) = 119 us; R6 (1 blk/CU,
// counted vmcnt) = 109 us; both pinned at ~2.5 TB/s. Theory: the fixes are
// complements -- counted waits keep each block's queue non-empty, a second
// co-resident block absorbs residual stalls. This round combines them:
//   grid 512 (2 blk/CU), 64-row tile, 64 KB LDS/block, BK=32:
//   phase 1: ring-3 of [x 64x32 bf16 (4 KB) + Wd 256x32 (16 KB)] = 60 KB,
//            depth-2 prefetch, in-loop s_waitcnt vmcnt(3) (never 0).
//   phase 2: Rs 64x256 (32 KB) + Wu 64-col chunk dbuf (2x32 KB) overlaid on
//            dead ring; af[2][8] in regs; q (residual x + bias) prefetched
//            one chunk ahead; in-loop vmcnt(8).
//   T5 setprio(1) around MFMA clusters (2 blk/CU gives role diversity).
// __launch_bounds__(512,4) caps VGPR at 128 so both blocks stay resident.
//
// Swizzle: 16-B slots in a row; phys_slot = slot XOR (row & 3) for BK=32
// tiles (4 slots/row), slot XOR (row&7) within 8-slot groups for 256-wide
// Rs/Wu tiles. DMA (linear LDS dest) gets the XOR on the global source col.

typedef unsigned short u16;
typedef __bf16 bf16x8 __attribute__((ext_vector_type(8)));
typedef float f32x4 __attribute__((ext_vector_type(4)));

__device__ __forceinline__ u16 f2bf(float f) {
    union { float f; unsigned int i; } v; v.f = f;
    unsigned int r = v.i + 0x7fffu + ((v.i >> 16) & 1u);  // RNE
    return (u16)(r >> 16);
}

__device__ __forceinline__ void gload_lds16(const u16* g, u16* l) {
    __builtin_amdgcn_global_load_lds(
        (const __attribute__((address_space(1))) void*)g,
        (__attribute__((address_space(3))) void*)l,
        16, 0, 0);
}

__device__ __forceinline__ void store4(u16* dst, float4 a) {
    union { uint2 u; u16 s[4]; } cv;
    cv.s[0]=f2bf(a.x); cv.s[1]=f2bf(a.y); cv.s[2]=f2bf(a.z); cv.s[3]=f2bf(a.w);
    *(uint2*)dst = cv.u;
}

#define MEMF() asm volatile("" ::: "memory")

__device__ __forceinline__ void barx() {
    asm volatile("" ::: "memory");
    __builtin_amdgcn_s_barrier();
    asm volatile("" ::: "memory");
}

// ---------------------------------------------------------------------------
// Kernel 0: merge weights + biases (fp32 in -> bf16 weights / fp32 biases).
// ---------------------------------------------------------------------------
__global__ __launch_bounds__(256)
void merge_kernel(const float* __restrict__ prob,
                  const float* __restrict__ w_down, const float* __restrict__ b_down,
                  const float* __restrict__ w_up,   const float* __restrict__ b_up,
                  u16* __restrict__ Wd, u16* __restrict__ Wu,
                  float* __restrict__ bd, float* __restrict__ bu)
{
    __shared__ float sp[128];          // prob (16 x 8)
    const int tid = threadIdx.x;
    if (tid < 128) sp[tid] = prob[tid];
    __syncthreads();

    const int bid = blockIdx.x;
    const int E = 256 * 1024;

    if (bid < 256) {
        int v = bid * 256 + tid;       // 0..65535 vector slots (8 elems each)
        const bool down = (v < 32768);
        const int vv = down ? v : (v - 32768);
        const float* W = down ? w_down : w_up;
        u16* O = down ? Wd : Wu;
        const size_t e = (size_t)vv * 8;

        float wf[8][8];
        #pragma unroll
        for (int k = 0; k < 8; ++k) {
            const float4 f0 = *(const float4*)(W + (size_t)k * E + e);
            const float4 f1 = *(const float4*)(W + (size_t)k * E + e + 4);
            wf[k][0] = f0.x; wf[k][1] = f0.y; wf[k][2] = f0.z; wf[k][3] = f0.w;
            wf[k][4] = f1.x; wf[k][5] = f1.y; wf[k][6] = f1.z; wf[k][7] = f1.w;
        }
        for (int n = 0; n < 16; ++n) {
            float a[8] = {0.f,0.f,0.f,0.f,0.f,0.f,0.f,0.f};
            #pragma unroll
            for (int k = 0; k < 8; ++k) {
                const float p = sp[n * 8 + k];
                #pragma unroll
                for (int j = 0; j < 8; ++j) a[j] = fmaf(p, wf[k][j], a[j]);
            }
            union { uint4 u; u16 s[8]; } ov;
            #pragma unroll
            for (int j = 0; j < 8; ++j) ov.s[j] = f2bf(a[j]);
            *(uint4*)(O + (size_t)n * E + e) = ov.u;
        }
    } else {
        int idx = (bid - 256) * 256 + tid;   // 0..20479
        if (idx < 16 * 256) {
            const int n = idx >> 8, d = idx & 255;
            float s = 0.f;
            #pragma unroll
            for (int k = 0; k < 8; ++k)
                s = fmaf(sp[n * 8 + k], b_down[k * 256 + d], s);
            bd[idx] = s;
        } else {
            const int i2 = idx - 4096;
            const int n = i2 >> 10, h = i2 & 1023;
            float s = 0.f;
            #pragma unroll
            for (int k = 0; k < 8; ++k)
                s = fmaf(sp[n * 8 + k], b_up[k * 1024 + h], s);
            bu[i2] = s;
        }
    }
}

// ---------------------------------------------------------------------------
// Fused adapter kernel. Grid 512 (2 blk/CU), 512 thr (8 waves), 64 KB LDS.
// ---------------------------------------------------------------------------
__global__ __launch_bounds__(512, 4)
void fused_adapter(const float* __restrict__ x, const u16* __restrict__ Wd,
                   const u16* __restrict__ Wu, const float* __restrict__ bd,
                   const float* __restrict__ bu, float* __restrict__ out)
{
    __shared__ __align__(16) u16 lds[32768];   // 64 KB

    const int tid  = threadIdx.x;
    const int lane = tid & 63;
    const int wave = tid >> 6;               // 0..7
    const int quad = lane >> 4, rl = lane & 15;
    const int rxl  = rl & 7;

    // XCD grouping: 2 batches per XCD -> Wd/Wu (1 MB/batch) L2-hot
    const int id = blockIdx.x;               // 0..511
    const int batch = (id & 7) * 2 + ((id >> 3) & 1);
    const int mblk  = id >> 4;               // 0..31

    const float* xb  = x  + (size_t)batch * 2048 * 1024 + (size_t)mblk * 64 * 1024;
    const u16*   Wdb = Wd + (size_t)batch * 256 * 1024;
    const u16*   Wub = Wu + (size_t)batch * 1024 * 256;
    const float* bdb = bd + batch * 256;
    const float* bub = bu + batch * 1024;
    float*       ob  = out + (size_t)batch * 2048 * 1024 + (size_t)mblk * 64 * 1024;

    // ring-3 buffers (u16 offsets): x 2048 + Wd 8192 each
    constexpr int XO[3] = {0, 10240, 20480};
    constexpr int WO[3] = {2048, 12288, 22528};

    // ============== phase 1: R = relu(x @ Wd^T + bd), ring-3, depth-2 ======
    const int wm1 = wave >> 2, wn1 = wave & 3;   // 2x4 over 64x256

    // x staging: 1 float4/thread -> 8 B bf16, swizzled half-slot
    const int xrow = tid >> 3;                  // 0..63
    const int xc4  = (tid & 7) * 4;             // fp32 col
    const int xs2  = (tid & 7) >> 1, xhalf = tid & 1;
    const int xdst = xrow * 32 + (xs2 ^ (xrow & 3)) * 8 + xhalf * 4;
    // Wd staging: 2 DMA/thread; pre-swizzled global col
    const int wswz = ((lane & 3) ^ ((lane >> 2) & 3)) * 8;

    // bias preload, fully retired before the pipeline (exact vmcnt counts)
    float bdv[4];
    #pragma unroll
    for (int ni = 0; ni < 4; ++ni) bdv[ni] = bdb[wn1 * 64 + ni * 16 + rl];
    asm volatile("s_waitcnt vmcnt(0)" ::: "memory");

    auto ldx = [&](int kt, float4& d) {
        d = *(const float4*)(xb + (size_t)xrow * 1024 + kt + xc4);
    };
    auto stx = [&](u16* xbuf, const float4& d) { store4(xbuf + xdst, d); };
    auto stage_wd = [&](int kt, u16* wbuf) {
        #pragma unroll
        for (int r = 0; r < 2; ++r)
            gload_lds16(Wdb + (size_t)((wave * 2 + r) * 16 + (lane >> 2)) * 1024
                            + kt + wswz,
                        wbuf + (wave * 2 + r) * 512);
    };

    f32x4 acc1[2][4] = {};
    auto comp1 = [&](const u16* xbuf, const u16* wbuf) {
        bf16x8 av[2], bv[4];
        #pragma unroll
        for (int mi = 0; mi < 2; ++mi) {
            const int row = wm1 * 32 + mi * 16 + rl;
            av[mi] = *(const bf16x8*)(xbuf + row * 32 + (quad ^ (row & 3)) * 8);
        }
        #pragma unroll
        for (int ni = 0; ni < 4; ++ni) {
            const int row = wn1 * 64 + ni * 16 + rl;
            bv[ni] = *(const bf16x8*)(wbuf + row * 32 + (quad ^ (row & 3)) * 8);
        }
        __builtin_amdgcn_s_setprio(1);
        #pragma unroll
        for (int mi = 0; mi < 2; ++mi)
            #pragma unroll
            for (int ni = 0; ni < 4; ++ni)
                acc1[mi][ni] = __builtin_amdgcn_mfma_f32_16x16x32_bf16(
                    av[mi], bv[ni], acc1[mi][ni], 0, 0, 0);
        __builtin_amdgcn_s_setprio(0);
    };

    // prologue: stage iters 0,1 (queue after: x0:1 D0:2 | x1:1 D1:2)
    float4 xa[2];
    ldx(0, xa[0]);  stage_wd(0, lds + WO[0]);
    MEMF();
    ldx(32, xa[1]); stage_wd(32, lds + WO[1]);
    asm volatile("s_waitcnt vmcnt(5)" ::: "memory");   // x0 done
    stx(lds + XO[0], xa[0]);
    asm volatile("s_waitcnt vmcnt(3)" ::: "memory");   // D0 done
    asm volatile("s_waitcnt lgkmcnt(0)" ::: "memory");
    barx();

    #pragma unroll
    for (int t = 0; t < 32; ++t) {
        const int cb = t % 3;
        if (t < 30) {
            ldx((t + 2) * 32, xa[t & 1]);                // x(t+2)
            stage_wd((t + 2) * 32, lds + WO[(t + 2) % 3]);  // D(t+2)
            MEMF();
        }
        comp1(lds + XO[cb], lds + WO[cb]);
        // retire x(t+1)+D(t+1); keep x(t+2)+D(t+2) in flight
        if (t < 30)       asm volatile("s_waitcnt vmcnt(3)" ::: "memory");
        else if (t == 30) asm volatile("s_waitcnt vmcnt(0)" ::: "memory");
        if (t < 31) {
            stx(lds + XO[(t + 1) % 3], xa[(t + 1) & 1]);
            asm volatile("s_waitcnt lgkmcnt(0)" ::: "memory");
        }
        barx();
    }

    // ============== phase 2: out = x + R @ Wu^T + bu =======================
    const int wm2 = wave >> 2, wn2 = wave & 3;   // rows 2x16, cols 16 per chunk
    const int srow = tid >> 5, ss = tid & 31;
    const int wugcol = ((ss & 24) | ((ss & 7) ^ (srow & 7))) * 8;
    u16* const wub0 = lds + 16384;
    u16* const wub1 = lds;                       // reuses Rs region after hoist

    auto stage_wu = [&](int c, u16* buf) {
        #pragma unroll
        for (int rr = 0; rr < 4; ++rr)
            gload_lds16(Wub + (size_t)(c * 64 + rr * 16 + srow) * 256 + wugcol,
                        buf + (size_t)(rr * 512 + wave * 64) * 8);
    };
    // residual x + bias prefetch for one chunk: 9 loads -> regs
    auto ldxqb = [&](int c, float* dq) {
        const int colg = c * 64 + wn2 * 16 + rl;
        #pragma unroll
        for (int mi = 0; mi < 2; ++mi)
            #pragma unroll
            for (int i = 0; i < 4; ++i)
                dq[mi * 4 + i] =
                    xb[(size_t)(wm2 * 32 + mi * 16 + quad * 4 + i) * 1024 + colg];
        dq[8] = bub[colg];
    };

    // transition: issue chunk-0 DMA + chunk-0 regs under epilogue-1's VALU
    stage_wu(0, wub0);      // D0: 4
    MEMF();
    float xq[2][9];
    ldxqb(0, xq[0]);        // q0: 9
    MEMF();

    // epilogue-1: bias + relu -> Rs at lds[0,16384) (ring bufs dead)
    #pragma unroll
    for (int ni = 0; ni < 4; ++ni) {
        const int col = wn1 * 64 + ni * 16 + rl;
        const int lbc = col >> 3, hi = lbc & 24, c7 = lbc & 7, cl = col & 7;
        #pragma unroll
        for (int mi = 0; mi < 2; ++mi)
            #pragma unroll
            for (int i = 0; i < 4; ++i) {
                const int row = wm1 * 32 + mi * 16 + quad * 4 + i;
                const int phys = hi | (c7 ^ (row & 7));
                lds[row * 256 + phys * 8 + cl] =
                    f2bf(fmaxf(acc1[mi][ni][i] + bdv[ni], 0.0f));
            }
    }
    asm volatile("s_waitcnt lgkmcnt(0)" ::: "memory");
    asm volatile("s_waitcnt vmcnt(9)" ::: "memory");   // D0 done, q0 may fly
    barx();

    // af hoist: R A-fragments to registers (64 VGPR); Rs then dead
    bf16x8 af[2][8];
    #pragma unroll
    for (int mi = 0; mi < 2; ++mi) {
        const int row = wm2 * 32 + mi * 16 + rl;
        #pragma unroll
        for (int t = 0; t < 8; ++t) {
            const int lb = t * 4 + quad;
            const int phys = (lb & 24) | ((lb & 7) ^ rxl);
            af[mi][t] = *(const bf16x8*)(lds + (row * 32 + phys) * 8);
        }
    }
    asm volatile("s_waitcnt lgkmcnt(0)" ::: "memory");
    barx();   // all waves done reading Rs; wub1 region now safe for DMA

    #pragma unroll
    for (int c = 0; c < 16; ++c) {
        const u16* wcur = (c & 1) ? wub1 : wub0;
        if (c < 15) {
            ldxqb(c + 1, xq[(c + 1) & 1]);               // q(c+1): 9
            MEMF();
            stage_wu(c + 1, (c & 1) ? wub0 : wub1);      // D(c+1): 4
            MEMF();
        }
        f32x4 acc2[2] = {};
        __builtin_amdgcn_s_setprio(1);
        #pragma unroll
        for (int t = 0; t < 8; ++t) {
            const int lb = t * 4 + quad;
            const int phys = (lb & 24) | ((lb & 7) ^ rxl);
            const bf16x8 bv = *(const bf16x8*)(wcur + (wn2 * 16 + rl) * 256
                                               + phys * 8);
            #pragma unroll
            for (int mi = 0; mi < 2; ++mi)
                acc2[mi] = __builtin_amdgcn_mfma_f32_16x16x32_bf16(
                    af[mi][t], bv, acc2[mi], 0, 0, 0);
        }
        __builtin_amdgcn_s_setprio(0);
        // chunk 0 only: retire q0 (queue: q0:9, q1:9, D1:4 -> keep 13)
        if (c == 0) asm volatile("s_waitcnt vmcnt(13)" ::: "memory");

        // epilogue-2: bias + fp32 residual -> fp32 out (8 stores)
        {
            const int colg = c * 64 + wn2 * 16 + rl;
            const float bval = xq[c & 1][8];
            #pragma unroll
            for (int mi = 0; mi < 2; ++mi)
                #pragma unroll
                for (int i = 0; i < 4; ++i) {
                    const int rowl = wm2 * 32 + mi * 16 + quad * 4 + i;
                    ob[(size_t)rowl * 1024 + colg] =
                        acc2[mi][i] + bval + xq[c & 1][mi * 4 + i];
                }
        }
        if (c < 15) {
            // retire q(c+1)+D(c+1)+stores(c-1); keep stores(c):8
            asm volatile("s_waitcnt vmcnt(8)" ::: "memory");
            barx();
        }
    }
}

// ---------------------------------------------------------------------------
extern "C" void kernel_launch(void* const* d_in, const int* in_sizes, int n_in,
                              void* d_out, int out_size, void* d_ws, size_t ws_size,
                              hipStream_t stream) {
    const float* hidden = (const float*)d_in[0];   // (16, 2048, 1024) fp32
    const float* prob   = (const float*)d_in[1];   // (16, 8) fp32
    const float* w_down = (const float*)d_in[2];   // (8, 256, 1024) fp32
    const float* b_down = (const float*)d_in[3];   // (8, 256) fp32
    const float* w_up   = (const float*)d_in[4];   // (8, 1024, 256) fp32
    const float* b_up   = (const float*)d_in[5];   // (8, 1024) fp32
    float* out = (float*)d_out;                    // (16, 2048, 1024) fp32

    // workspace: merged weights (bf16) + biases (fp32), ~16.1 MB
    u16* Wd = (u16*)d_ws;                               // 16*256*1024 bf16
    u16* Wu = Wd + (size_t)16 * 256 * 1024;             // 16*1024*256 bf16
    float* bd = (float*)(Wu + (size_t)16 * 1024 * 256); // 16*256 f32
    float* bu = bd + 16 * 256;                          // 16*1024 f32

    merge_kernel<<<336, 256, 0, stream>>>(prob, w_down, b_down, w_up, b_up,
                                          Wd, Wu, bd, bu);

    fused_adapter<<<512, 512, 0, stream>>>(hidden, Wd, Wu, bd, bu, out);
}

// Round 7
// 458.464 us; speedup vs baseline: 1.0104x; 1.0104x over previous
//
#include <hip/hip_runtime.h>

// MergeAdapter: out = x + Up_n(relu(Down_n(x))), merged expert weights.
// N=16, S=2048, H=1024, Kexp=8, D=256. fp32 in/out, bf16 MFMA internally.
//
// Round 8 (resubmit; prior attempt hit GPUAcquisitionTimeout, never ran).
// R7 spill fix. R7 (2 blk/CU + counted vmcnt) regressed to 279 us
// NOT because the structure was wrong but because __launch_bounds__(512,4)
// (a MINIMUM of 4 waves/EU) let the allocator squeeze to 64 VGPR for the
// 8-waves/EU tier, spilling af[]/xq[] inside the chunk loop: FETCH/WRITE
// both inflated ~195 MB (744 B/thread of scratch round trips), MfmaUtil
// 4.9%. Fix: __launch_bounds__(512) + amdgpu_waves_per_eu(4,4) -- explicit
// max 4 w/EU => allocator targets the 128-reg cap (R6 used 100 for the same
// state size), no spill, 2 blocks/CU preserved. Everything else identical
// to R7:
//   grid 512 (2 blk/CU), 64-row tile, 64 KB LDS/block, BK=32:
//   phase 1: ring-3 of [x 64x32 bf16 (4 KB) + Wd 256x32 (16 KB)] = 60 KB,
//            depth-2 prefetch, in-loop s_waitcnt vmcnt(3) (never 0).
//   phase 2: Rs 64x256 (32 KB) + Wu 64-col chunk dbuf (2x32 KB) overlaid on
//            dead ring; af[2][8] in regs; q (residual x + bias) prefetched
//            one chunk ahead; in-loop vmcnt(8).
//   T5 setprio(1) around MFMA clusters.

typedef unsigned short u16;
typedef __bf16 bf16x8 __attribute__((ext_vector_type(8)));
typedef float f32x4 __attribute__((ext_vector_type(4)));

__device__ __forceinline__ u16 f2bf(float f) {
    union { float f; unsigned int i; } v; v.f = f;
    unsigned int r = v.i + 0x7fffu + ((v.i >> 16) & 1u);  // RNE
    return (u16)(r >> 16);
}

__device__ __forceinline__ void gload_lds16(const u16* g, u16* l) {
    __builtin_amdgcn_global_load_lds(
        (const __attribute__((address_space(1))) void*)g,
        (__attribute__((address_space(3))) void*)l,
        16, 0, 0);
}

__device__ __forceinline__ void store4(u16* dst, float4 a) {
    union { uint2 u; u16 s[4]; } cv;
    cv.s[0]=f2bf(a.x); cv.s[1]=f2bf(a.y); cv.s[2]=f2bf(a.z); cv.s[3]=f2bf(a.w);
    *(uint2*)dst = cv.u;
}

#define MEMF() asm volatile("" ::: "memory")

__device__ __forceinline__ void barx() {
    asm volatile("" ::: "memory");
    __builtin_amdgcn_s_barrier();
    asm volatile("" ::: "memory");
}

// ---------------------------------------------------------------------------
// Kernel 0: merge weights + biases (fp32 in -> bf16 weights / fp32 biases).
// ---------------------------------------------------------------------------
__global__ __launch_bounds__(256)
void merge_kernel(const float* __restrict__ prob,
                  const float* __restrict__ w_down, const float* __restrict__ b_down,
                  const float* __restrict__ w_up,   const float* __restrict__ b_up,
                  u16* __restrict__ Wd, u16* __restrict__ Wu,
                  float* __restrict__ bd, float* __restrict__ bu)
{
    __shared__ float sp[128];          // prob (16 x 8)
    const int tid = threadIdx.x;
    if (tid < 128) sp[tid] = prob[tid];
    __syncthreads();

    const int bid = blockIdx.x;
    const int E = 256 * 1024;

    if (bid < 256) {
        int v = bid * 256 + tid;       // 0..65535 vector slots (8 elems each)
        const bool down = (v < 32768);
        const int vv = down ? v : (v - 32768);
        const float* W = down ? w_down : w_up;
        u16* O = down ? Wd : Wu;
        const size_t e = (size_t)vv * 8;

        float wf[8][8];
        #pragma unroll
        for (int k = 0; k < 8; ++k) {
            const float4 f0 = *(const float4*)(W + (size_t)k * E + e);
            const float4 f1 = *(const float4*)(W + (size_t)k * E + e + 4);
            wf[k][0] = f0.x; wf[k][1] = f0.y; wf[k][2] = f0.z; wf[k][3] = f0.w;
            wf[k][4] = f1.x; wf[k][5] = f1.y; wf[k][6] = f1.z; wf[k][7] = f1.w;
        }
        for (int n = 0; n < 16; ++n) {
            float a[8] = {0.f,0.f,0.f,0.f,0.f,0.f,0.f,0.f};
            #pragma unroll
            for (int k = 0; k < 8; ++k) {
                const float p = sp[n * 8 + k];
                #pragma unroll
                for (int j = 0; j < 8; ++j) a[j] = fmaf(p, wf[k][j], a[j]);
            }
            union { uint4 u; u16 s[8]; } ov;
            #pragma unroll
            for (int j = 0; j < 8; ++j) ov.s[j] = f2bf(a[j]);
            *(uint4*)(O + (size_t)n * E + e) = ov.u;
        }
    } else {
        int idx = (bid - 256) * 256 + tid;   // 0..20479
        if (idx < 16 * 256) {
            const int n = idx >> 8, d = idx & 255;
            float s = 0.f;
            #pragma unroll
            for (int k = 0; k < 8; ++k)
                s = fmaf(sp[n * 8 + k], b_down[k * 256 + d], s);
            bd[idx] = s;
        } else {
            const int i2 = idx - 4096;
            const int n = i2 >> 10, h = i2 & 1023;
            float s = 0.f;
            #pragma unroll
            for (int k = 0; k < 8; ++k)
                s = fmaf(sp[n * 8 + k], b_up[k * 1024 + h], s);
            bu[i2] = s;
        }
    }
}

// ---------------------------------------------------------------------------
// Fused adapter kernel. Grid 512 (2 blk/CU), 512 thr (8 waves), 64 KB LDS.
// ---------------------------------------------------------------------------
__global__ __launch_bounds__(512) __attribute__((amdgpu_waves_per_eu(4, 4)))
void fused_adapter(const float* __restrict__ x, const u16* __restrict__ Wd,
                   const u16* __restrict__ Wu, const float* __restrict__ bd,
                   const float* __restrict__ bu, float* __restrict__ out)
{
    __shared__ __align__(16) u16 lds[32768];   // 64 KB

    const int tid  = threadIdx.x;
    const int lane = tid & 63;
    const int wave = tid >> 6;               // 0..7
    const int quad = lane >> 4, rl = lane & 15;
    const int rxl  = rl & 7;

    // XCD grouping: 2 batches per XCD -> Wd/Wu (1 MB/batch) L2-hot
    const int id = blockIdx.x;               // 0..511
    const int batch = (id & 7) * 2 + ((id >> 3) & 1);
    const int mblk  = id >> 4;               // 0..31

    const float* xb  = x  + (size_t)batch * 2048 * 1024 + (size_t)mblk * 64 * 1024;
    const u16*   Wdb = Wd + (size_t)batch * 256 * 1024;
    const u16*   Wub = Wu + (size_t)batch * 1024 * 256;
    const float* bdb = bd + batch * 256;
    const float* bub = bu + batch * 1024;
    float*       ob  = out + (size_t)batch * 2048 * 1024 + (size_t)mblk * 64 * 1024;

    // ring-3 buffers (u16 offsets): x 2048 + Wd 8192 each
    constexpr int XO[3] = {0, 10240, 20480};
    constexpr int WO[3] = {2048, 12288, 22528};

    // ============== phase 1: R = relu(x @ Wd^T + bd), ring-3, depth-2 ======
    const int wm1 = wave >> 2, wn1 = wave & 3;   // 2x4 over 64x256

    // x staging: 1 float4/thread -> 8 B bf16, swizzled half-slot
    const int xrow = tid >> 3;                  // 0..63
    const int xc4  = (tid & 7) * 4;             // fp32 col
    const int xs2  = (tid & 7) >> 1, xhalf = tid & 1;
    const int xdst = xrow * 32 + (xs2 ^ (xrow & 3)) * 8 + xhalf * 4;
    // Wd staging: 2 DMA/thread; pre-swizzled global col
    const int wswz = ((lane & 3) ^ ((lane >> 2) & 3)) * 8;

    // bias preload, fully retired before the pipeline (exact vmcnt counts)
    float bdv[4];
    #pragma unroll
    for (int ni = 0; ni < 4; ++ni) bdv[ni] = bdb[wn1 * 64 + ni * 16 + rl];
    asm volatile("s_waitcnt vmcnt(0)" ::: "memory");

    auto ldx = [&](int kt, float4& d) {
        d = *(const float4*)(xb + (size_t)xrow * 1024 + kt + xc4);
    };
    auto stx = [&](u16* xbuf, const float4& d) { store4(xbuf + xdst, d); };
    auto stage_wd = [&](int kt, u16* wbuf) {
        #pragma unroll
        for (int r = 0; r < 2; ++r)
            gload_lds16(Wdb + (size_t)((wave * 2 + r) * 16 + (lane >> 2)) * 1024
                            + kt + wswz,
                        wbuf + (wave * 2 + r) * 512);
    };

    f32x4 acc1[2][4] = {};
    auto comp1 = [&](const u16* xbuf, const u16* wbuf) {
        bf16x8 av[2], bv[4];
        #pragma unroll
        for (int mi = 0; mi < 2; ++mi) {
            const int row = wm1 * 32 + mi * 16 + rl;
            av[mi] = *(const bf16x8*)(xbuf + row * 32 + (quad ^ (row & 3)) * 8);
        }
        #pragma unroll
        for (int ni = 0; ni < 4; ++ni) {
            const int row = wn1 * 64 + ni * 16 + rl;
            bv[ni] = *(const bf16x8*)(wbuf + row * 32 + (quad ^ (row & 3)) * 8);
        }
        __builtin_amdgcn_s_setprio(1);
        #pragma unroll
        for (int mi = 0; mi < 2; ++mi)
            #pragma unroll
            for (int ni = 0; ni < 4; ++ni)
                acc1[mi][ni] = __builtin_amdgcn_mfma_f32_16x16x32_bf16(
                    av[mi], bv[ni], acc1[mi][ni], 0, 0, 0);
        __builtin_amdgcn_s_setprio(0);
    };

    // prologue: stage iters 0,1 (queue after: x0:1 D0:2 | x1:1 D1:2)
    float4 xa[2];
    ldx(0, xa[0]);  stage_wd(0, lds + WO[0]);
    MEMF();
    ldx(32, xa[1]); stage_wd(32, lds + WO[1]);
    asm volatile("s_waitcnt vmcnt(5)" ::: "memory");   // x0 done
    stx(lds + XO[0], xa[0]);
    asm volatile("s_waitcnt vmcnt(3)" ::: "memory");   // D0 done
    asm volatile("s_waitcnt lgkmcnt(0)" ::: "memory");
    barx();

    #pragma unroll
    for (int t = 0; t < 32; ++t) {
        const int cb = t % 3;
        if (t < 30) {
            ldx((t + 2) * 32, xa[t & 1]);                // x(t+2)
            stage_wd((t + 2) * 32, lds + WO[(t + 2) % 3]);  // D(t+2)
            MEMF();
        }
        comp1(lds + XO[cb], lds + WO[cb]);
        // retire x(t+1)+D(t+1); keep x(t+2)+D(t+2) in flight
        if (t < 30)       asm volatile("s_waitcnt vmcnt(3)" ::: "memory");
        else if (t == 30) asm volatile("s_waitcnt vmcnt(0)" ::: "memory");
        if (t < 31) {
            stx(lds + XO[(t + 1) % 3], xa[(t + 1) & 1]);
            asm volatile("s_waitcnt lgkmcnt(0)" ::: "memory");
        }
        barx();
    }

    // ============== phase 2: out = x + R @ Wu^T + bu =======================
    const int wm2 = wave >> 2, wn2 = wave & 3;   // rows 2x16, cols 16 per chunk
    const int srow = tid >> 5, ss = tid & 31;
    const int wugcol = ((ss & 24) | ((ss & 7) ^ (srow & 7))) * 8;
    u16* const wub0 = lds + 16384;
    u16* const wub1 = lds;                       // reuses Rs region after hoist

    auto stage_wu = [&](int c, u16* buf) {
        #pragma unroll
        for (int rr = 0; rr < 4; ++rr)
            gload_lds16(Wub + (size_t)(c * 64 + rr * 16 + srow) * 256 + wugcol,
                        buf + (size_t)(rr * 512 + wave * 64) * 8);
    };
    // residual x + bias prefetch for one chunk: 9 loads -> regs
    auto ldxqb = [&](int c, float* dq) {
        const int colg = c * 64 + wn2 * 16 + rl;
        #pragma unroll
        for (int mi = 0; mi < 2; ++mi)
            #pragma unroll
            for (int i = 0; i < 4; ++i)
                dq[mi * 4 + i] =
                    xb[(size_t)(wm2 * 32 + mi * 16 + quad * 4 + i) * 1024 + colg];
        dq[8] = bub[colg];
    };

    // transition: issue chunk-0 DMA + chunk-0 regs under epilogue-1's VALU
    stage_wu(0, wub0);      // D0: 4
    MEMF();
    float xq[2][9];
    ldxqb(0, xq[0]);        // q0: 9
    MEMF();

    // epilogue-1: bias + relu -> Rs at lds[0,16384) (ring bufs dead)
    #pragma unroll
    for (int ni = 0; ni < 4; ++ni) {
        const int col = wn1 * 64 + ni * 16 + rl;
        const int lbc = col >> 3, hi = lbc & 24, c7 = lbc & 7, cl = col & 7;
        #pragma unroll
        for (int mi = 0; mi < 2; ++mi)
            #pragma unroll
            for (int i = 0; i < 4; ++i) {
                const int row = wm1 * 32 + mi * 16 + quad * 4 + i;
                const int phys = hi | (c7 ^ (row & 7));
                lds[row * 256 + phys * 8 + cl] =
                    f2bf(fmaxf(acc1[mi][ni][i] + bdv[ni], 0.0f));
            }
    }
    asm volatile("s_waitcnt lgkmcnt(0)" ::: "memory");
    asm volatile("s_waitcnt vmcnt(9)" ::: "memory");   // D0 done, q0 may fly
    barx();

    // af hoist: R A-fragments to registers (64 VGPR); Rs then dead
    bf16x8 af[2][8];
    #pragma unroll
    for (int mi = 0; mi < 2; ++mi) {
        const int row = wm2 * 32 + mi * 16 + rl;
        #pragma unroll
        for (int t = 0; t < 8; ++t) {
            const int lb = t * 4 + quad;
            const int phys = (lb & 24) | ((lb & 7) ^ rxl);
            af[mi][t] = *(const bf16x8*)(lds + (row * 32 + phys) * 8);
        }
    }
    asm volatile("s_waitcnt lgkmcnt(0)" ::: "memory");
    barx();   // all waves done reading Rs; wub1 region now safe for DMA

    #pragma unroll
    for (int c = 0; c < 16; ++c) {
        const u16* wcur = (c & 1) ? wub1 : wub0;
        if (c < 15) {
            ldxqb(c + 1, xq[(c + 1) & 1]);               // q(c+1): 9
            MEMF();
            stage_wu(c + 1, (c & 1) ? wub0 : wub1);      // D(c+1): 4
            MEMF();
        }
        f32x4 acc2[2] = {};
        __builtin_amdgcn_s_setprio(1);
        #pragma unroll
        for (int t = 0; t < 8; ++t) {
            const int lb = t * 4 + quad;
            const int phys = (lb & 24) | ((lb & 7) ^ rxl);
            const bf16x8 bv = *(const bf16x8*)(wcur + (wn2 * 16 + rl) * 256
                                               + phys * 8);
            #pragma unroll
            for (int mi = 0; mi < 2; ++mi)
                acc2[mi] = __builtin_amdgcn_mfma_f32_16x16x32_bf16(
                    af[mi][t], bv, acc2[mi], 0, 0, 0);
        }
        __builtin_amdgcn_s_setprio(0);
        // chunk 0 only: retire q0 (queue: q0:9, q1:9, D1:4 -> keep 13)
        if (c == 0) asm volatile("s_waitcnt vmcnt(13)" ::: "memory");

        // epilogue-2: bias + fp32 residual -> fp32 out (8 stores)
        {
            const int colg = c * 64 + wn2 * 16 + rl;
            const float bval = xq[c & 1][8];
            #pragma unroll
            for (int mi = 0; mi < 2; ++mi)
                #pragma unroll
                for (int i = 0; i < 4; ++i) {
                    const int rowl = wm2 * 32 + mi * 16 + quad * 4 + i;
                    ob[(size_t)rowl * 1024 + colg] =
                        acc2[mi][i] + bval + xq[c & 1][mi * 4 + i];
                }
        }
        if (c < 15) {
            // retire q(c+1)+D(c+1)+stores(c-1); keep stores(c):8
            asm volatile("s_waitcnt vmcnt(8)" ::: "memory");
            barx();
        }
    }
}

// ---------------------------------------------------------------------------
extern "C" void kernel_launch(void* const* d_in, const int* in_sizes, int n_in,
                              void* d_out, int out_size, void* d_ws, size_t ws_size,
                              hipStream_t stream) {
    const float* hidden = (const float*)d_in[0];   // (16, 2048, 1024) fp32
    const float* prob   = (const float*)d_in[1];   // (16, 8) fp32
    const float* w_down = (const float*)d_in[2];   // (8, 256, 1024) fp32
    const float* b_down = (const float*)d_in[3];   // (8, 256) fp32
    const float* w_up   = (const float*)d_in[4];   // (8, 1024, 256) fp32
    const float* b_up   = (const float*)d_in[5];   // (8, 1024) fp32
    float* out = (float*)d_out;                    // (16, 2048, 1024) fp32

    // workspace: merged weights (bf16) + biases (fp32), ~16.1 MB
    u16* Wd = (u16*)d_ws;                               // 16*256*1024 bf16
    u16* Wu = Wd + (size_t)16 * 256 * 1024;             // 16*1024*256 bf16
    float* bd = (float*)(Wu + (size_t)16 * 1024 * 256); // 16*256 f32
    float* bu = bd + 16 * 256;                          // 16*1024 f32

    merge_kernel<<<336, 256, 0, stream>>>(prob, w_down, b_down, w_up, b_up,
                                          Wd, Wu, bd, bu);

    fused_adapter<<<512, 512, 0, stream>>>(hidden, Wd, Wu, bd, bu, out);
}

// Round 8
// 335.425 us; speedup vs baseline: 1.3810x; 1.3668x over previous
//
#include <hip/hip_runtime.h>

// MergeAdapter: out = x + Up_n(relu(Down_n(x))), merged expert weights.
// N=16, S=2048, H=1024, Kexp=8, D=256. fp32 in/out, bf16 MFMA internally.
//
// Round 9: occupancy annotation fix, attempt 2. R7 (__launch_bounds__(512,4))
// and R8 (amdgpu_waves_per_eu(4,4)) both made the allocator pick the
// 64-VGPR / 8-waves-per-EU tier and spill af[]/xq[] (~195 MB extra FETCH
// AND WRITE, MfmaUtil 4.9%, identical counters both rounds) -- the backend
// chases the higher wave tier even though 64 KB LDS caps us at 2 blk/CU.
// The only proven-no-spill config is R6's __launch_bounds__(512,2): the
// compiler chose 100 VGPR there. At ~100 VGPR the HW tier is 16 waves/CU
// (halving thresholds 64/128/256, m69) = 2 blocks of 512, and 64 KB LDS
// also admits exactly 2 blocks -> 2 blk/CU happens naturally at runtime.
// Single change from R8: bounds -> (512,2), attribute removed.
// Structure unchanged:
//   grid 512 (2 blk/CU), 64-row tile, 64 KB LDS/block, BK=32:
//   phase 1: ring-3 of [x 64x32 bf16 (4 KB) + Wd 256x32 (16 KB)] = 60 KB,
//            depth-2 prefetch, in-loop s_waitcnt vmcnt(3) (never 0).
//   phase 2: Rs 64x256 (32 KB) + Wu 64-col chunk dbuf (2x32 KB) overlaid on
//            dead ring; af[2][8] in regs; q (residual x + bias) prefetched
//            one chunk ahead; in-loop vmcnt(8).
//   T5 setprio(1) around MFMA clusters.

typedef unsigned short u16;
typedef __bf16 bf16x8 __attribute__((ext_vector_type(8)));
typedef float f32x4 __attribute__((ext_vector_type(4)));

__device__ __forceinline__ u16 f2bf(float f) {
    union { float f; unsigned int i; } v; v.f = f;
    unsigned int r = v.i + 0x7fffu + ((v.i >> 16) & 1u);  // RNE
    return (u16)(r >> 16);
}

__device__ __forceinline__ void gload_lds16(const u16* g, u16* l) {
    __builtin_amdgcn_global_load_lds(
        (const __attribute__((address_space(1))) void*)g,
        (__attribute__((address_space(3))) void*)l,
        16, 0, 0);
}

__device__ __forceinline__ void store4(u16* dst, float4 a) {
    union { uint2 u; u16 s[4]; } cv;
    cv.s[0]=f2bf(a.x); cv.s[1]=f2bf(a.y); cv.s[2]=f2bf(a.z); cv.s[3]=f2bf(a.w);
    *(uint2*)dst = cv.u;
}

#define MEMF() asm volatile("" ::: "memory")

__device__ __forceinline__ void barx() {
    asm volatile("" ::: "memory");
    __builtin_amdgcn_s_barrier();
    asm volatile("" ::: "memory");
}

// ---------------------------------------------------------------------------
// Kernel 0: merge weights + biases (fp32 in -> bf16 weights / fp32 biases).
// ---------------------------------------------------------------------------
__global__ __launch_bounds__(256)
void merge_kernel(const float* __restrict__ prob,
                  const float* __restrict__ w_down, const float* __restrict__ b_down,
                  const float* __restrict__ w_up,   const float* __restrict__ b_up,
                  u16* __restrict__ Wd, u16* __restrict__ Wu,
                  float* __restrict__ bd, float* __restrict__ bu)
{
    __shared__ float sp[128];          // prob (16 x 8)
    const int tid = threadIdx.x;
    if (tid < 128) sp[tid] = prob[tid];
    __syncthreads();

    const int bid = blockIdx.x;
    const int E = 256 * 1024;

    if (bid < 256) {
        int v = bid * 256 + tid;       // 0..65535 vector slots (8 elems each)
        const bool down = (v < 32768);
        const int vv = down ? v : (v - 32768);
        const float* W = down ? w_down : w_up;
        u16* O = down ? Wd : Wu;
        const size_t e = (size_t)vv * 8;

        float wf[8][8];
        #pragma unroll
        for (int k = 0; k < 8; ++k) {
            const float4 f0 = *(const float4*)(W + (size_t)k * E + e);
            const float4 f1 = *(const float4*)(W + (size_t)k * E + e + 4);
            wf[k][0] = f0.x; wf[k][1] = f0.y; wf[k][2] = f0.z; wf[k][3] = f0.w;
            wf[k][4] = f1.x; wf[k][5] = f1.y; wf[k][6] = f1.z; wf[k][7] = f1.w;
        }
        for (int n = 0; n < 16; ++n) {
            float a[8] = {0.f,0.f,0.f,0.f,0.f,0.f,0.f,0.f};
            #pragma unroll
            for (int k = 0; k < 8; ++k) {
                const float p = sp[n * 8 + k];
                #pragma unroll
                for (int j = 0; j < 8; ++j) a[j] = fmaf(p, wf[k][j], a[j]);
            }
            union { uint4 u; u16 s[8]; } ov;
            #pragma unroll
            for (int j = 0; j < 8; ++j) ov.s[j] = f2bf(a[j]);
            *(uint4*)(O + (size_t)n * E + e) = ov.u;
        }
    } else {
        int idx = (bid - 256) * 256 + tid;   // 0..20479
        if (idx < 16 * 256) {
            const int n = idx >> 8, d = idx & 255;
            float s = 0.f;
            #pragma unroll
            for (int k = 0; k < 8; ++k)
                s = fmaf(sp[n * 8 + k], b_down[k * 256 + d], s);
            bd[idx] = s;
        } else {
            const int i2 = idx - 4096;
            const int n = i2 >> 10, h = i2 & 1023;
            float s = 0.f;
            #pragma unroll
            for (int k = 0; k < 8; ++k)
                s = fmaf(sp[n * 8 + k], b_up[k * 1024 + h], s);
            bu[i2] = s;
        }
    }
}

// ---------------------------------------------------------------------------
// Fused adapter kernel. Grid 512 (2 blk/CU via VGPR-tier + 64 KB LDS),
// 512 thr (8 waves).
// ---------------------------------------------------------------------------
__global__ __launch_bounds__(512, 2)
void fused_adapter(const float* __restrict__ x, const u16* __restrict__ Wd,
                   const u16* __restrict__ Wu, const float* __restrict__ bd,
                   const float* __restrict__ bu, float* __restrict__ out)
{
    __shared__ __align__(16) u16 lds[32768];   // 64 KB

    const int tid  = threadIdx.x;
    const int lane = tid & 63;
    const int wave = tid >> 6;               // 0..7
    const int quad = lane >> 4, rl = lane & 15;
    const int rxl  = rl & 7;

    // XCD grouping: 2 batches per XCD -> Wd/Wu (1 MB/batch) L2-hot
    const int id = blockIdx.x;               // 0..511
    const int batch = (id & 7) * 2 + ((id >> 3) & 1);
    const int mblk  = id >> 4;               // 0..31

    const float* xb  = x  + (size_t)batch * 2048 * 1024 + (size_t)mblk * 64 * 1024;
    const u16*   Wdb = Wd + (size_t)batch * 256 * 1024;
    const u16*   Wub = Wu + (size_t)batch * 1024 * 256;
    const float* bdb = bd + batch * 256;
    const float* bub = bu + batch * 1024;
    float*       ob  = out + (size_t)batch * 2048 * 1024 + (size_t)mblk * 64 * 1024;

    // ring-3 buffers (u16 offsets): x 2048 + Wd 8192 each
    constexpr int XO[3] = {0, 10240, 20480};
    constexpr int WO[3] = {2048, 12288, 22528};

    // ============== phase 1: R = relu(x @ Wd^T + bd), ring-3, depth-2 ======
    const int wm1 = wave >> 2, wn1 = wave & 3;   // 2x4 over 64x256

    // x staging: 1 float4/thread -> 8 B bf16, swizzled half-slot
    const int xrow = tid >> 3;                  // 0..63
    const int xc4  = (tid & 7) * 4;             // fp32 col
    const int xs2  = (tid & 7) >> 1, xhalf = tid & 1;
    const int xdst = xrow * 32 + (xs2 ^ (xrow & 3)) * 8 + xhalf * 4;
    // Wd staging: 2 DMA/thread; pre-swizzled global col
    const int wswz = ((lane & 3) ^ ((lane >> 2) & 3)) * 8;

    // bias preload, fully retired before the pipeline (exact vmcnt counts)
    float bdv[4];
    #pragma unroll
    for (int ni = 0; ni < 4; ++ni) bdv[ni] = bdb[wn1 * 64 + ni * 16 + rl];
    asm volatile("s_waitcnt vmcnt(0)" ::: "memory");

    auto ldx = [&](int kt, float4& d) {
        d = *(const float4*)(xb + (size_t)xrow * 1024 + kt + xc4);
    };
    auto stx = [&](u16* xbuf, const float4& d) { store4(xbuf + xdst, d); };
    auto stage_wd = [&](int kt, u16* wbuf) {
        #pragma unroll
        for (int r = 0; r < 2; ++r)
            gload_lds16(Wdb + (size_t)((wave * 2 + r) * 16 + (lane >> 2)) * 1024
                            + kt + wswz,
                        wbuf + (wave * 2 + r) * 512);
    };

    f32x4 acc1[2][4] = {};
    auto comp1 = [&](const u16* xbuf, const u16* wbuf) {
        bf16x8 av[2], bv[4];
        #pragma unroll
        for (int mi = 0; mi < 2; ++mi) {
            const int row = wm1 * 32 + mi * 16 + rl;
            av[mi] = *(const bf16x8*)(xbuf + row * 32 + (quad ^ (row & 3)) * 8);
        }
        #pragma unroll
        for (int ni = 0; ni < 4; ++ni) {
            const int row = wn1 * 64 + ni * 16 + rl;
            bv[ni] = *(const bf16x8*)(wbuf + row * 32 + (quad ^ (row & 3)) * 8);
        }
        __builtin_amdgcn_s_setprio(1);
        #pragma unroll
        for (int mi = 0; mi < 2; ++mi)
            #pragma unroll
            for (int ni = 0; ni < 4; ++ni)
                acc1[mi][ni] = __builtin_amdgcn_mfma_f32_16x16x32_bf16(
                    av[mi], bv[ni], acc1[mi][ni], 0, 0, 0);
        __builtin_amdgcn_s_setprio(0);
    };

    // prologue: stage iters 0,1 (queue after: x0:1 D0:2 | x1:1 D1:2)
    float4 xa[2];
    ldx(0, xa[0]);  stage_wd(0, lds + WO[0]);
    MEMF();
    ldx(32, xa[1]); stage_wd(32, lds + WO[1]);
    asm volatile("s_waitcnt vmcnt(5)" ::: "memory");   // x0 done
    stx(lds + XO[0], xa[0]);
    asm volatile("s_waitcnt vmcnt(3)" ::: "memory");   // D0 done
    asm volatile("s_waitcnt lgkmcnt(0)" ::: "memory");
    barx();

    #pragma unroll
    for (int t = 0; t < 32; ++t) {
        const int cb = t % 3;
        if (t < 30) {
            ldx((t + 2) * 32, xa[t & 1]);                // x(t+2)
            stage_wd((t + 2) * 32, lds + WO[(t + 2) % 3]);  // D(t+2)
            MEMF();
        }
        comp1(lds + XO[cb], lds + WO[cb]);
        // retire x(t+1)+D(t+1); keep x(t+2)+D(t+2) in flight
        if (t < 30)       asm volatile("s_waitcnt vmcnt(3)" ::: "memory");
        else if (t == 30) asm volatile("s_waitcnt vmcnt(0)" ::: "memory");
        if (t < 31) {
            stx(lds + XO[(t + 1) % 3], xa[(t + 1) & 1]);
            asm volatile("s_waitcnt lgkmcnt(0)" ::: "memory");
        }
        barx();
    }

    // ============== phase 2: out = x + R @ Wu^T + bu =======================
    const int wm2 = wave >> 2, wn2 = wave & 3;   // rows 2x16, cols 16 per chunk
    const int srow = tid >> 5, ss = tid & 31;
    const int wugcol = ((ss & 24) | ((ss & 7) ^ (srow & 7))) * 8;
    u16* const wub0 = lds + 16384;
    u16* const wub1 = lds;                       // reuses Rs region after hoist

    auto stage_wu = [&](int c, u16* buf) {
        #pragma unroll
        for (int rr = 0; rr < 4; ++rr)
            gload_lds16(Wub + (size_t)(c * 64 + rr * 16 + srow) * 256 + wugcol,
                        buf + (size_t)(rr * 512 + wave * 64) * 8);
    };
    // residual x + bias prefetch for one chunk: 9 loads -> regs
    auto ldxqb = [&](int c, float* dq) {
        const int colg = c * 64 + wn2 * 16 + rl;
        #pragma unroll
        for (int mi = 0; mi < 2; ++mi)
            #pragma unroll
            for (int i = 0; i < 4; ++i)
                dq[mi * 4 + i] =
                    xb[(size_t)(wm2 * 32 + mi * 16 + quad * 4 + i) * 1024 + colg];
        dq[8] = bub[colg];
    };

    // transition: issue chunk-0 DMA + chunk-0 regs under epilogue-1's VALU
    stage_wu(0, wub0);      // D0: 4
    MEMF();
    float xq[2][9];
    ldxqb(0, xq[0]);        // q0: 9
    MEMF();

    // epilogue-1: bias + relu -> Rs at lds[0,16384) (ring bufs dead)
    #pragma unroll
    for (int ni = 0; ni < 4; ++ni) {
        const int col = wn1 * 64 + ni * 16 + rl;
        const int lbc = col >> 3, hi = lbc & 24, c7 = lbc & 7, cl = col & 7;
        #pragma unroll
        for (int mi = 0; mi < 2; ++mi)
            #pragma unroll
            for (int i = 0; i < 4; ++i) {
                const int row = wm1 * 32 + mi * 16 + quad * 4 + i;
                const int phys = hi | (c7 ^ (row & 7));
                lds[row * 256 + phys * 8 + cl] =
                    f2bf(fmaxf(acc1[mi][ni][i] + bdv[ni], 0.0f));
            }
    }
    asm volatile("s_waitcnt lgkmcnt(0)" ::: "memory");
    asm volatile("s_waitcnt vmcnt(9)" ::: "memory");   // D0 done, q0 may fly
    barx();

    // af hoist: R A-fragments to registers (64 VGPR); Rs then dead
    bf16x8 af[2][8];
    #pragma unroll
    for (int mi = 0; mi < 2; ++mi) {
        const int row = wm2 * 32 + mi * 16 + rl;
        #pragma unroll
        for (int t = 0; t < 8; ++t) {
            const int lb = t * 4 + quad;
            const int phys = (lb & 24) | ((lb & 7) ^ rxl);
            af[mi][t] = *(const bf16x8*)(lds + (row * 32 + phys) * 8);
        }
    }
    asm volatile("s_waitcnt lgkmcnt(0)" ::: "memory");
    barx();   // all waves done reading Rs; wub1 region now safe for DMA

    #pragma unroll
    for (int c = 0; c < 16; ++c) {
        const u16* wcur = (c & 1) ? wub1 : wub0;
        if (c < 15) {
            ldxqb(c + 1, xq[(c + 1) & 1]);               // q(c+1): 9
            MEMF();
            stage_wu(c + 1, (c & 1) ? wub0 : wub1);      // D(c+1): 4
            MEMF();
        }
        f32x4 acc2[2] = {};
        __builtin_amdgcn_s_setprio(1);
        #pragma unroll
        for (int t = 0; t < 8; ++t) {
            const int lb = t * 4 + quad;
            const int phys = (lb & 24) | ((lb & 7) ^ rxl);
            const bf16x8 bv = *(const bf16x8*)(wcur + (wn2 * 16 + rl) * 256
                                               + phys * 8);
            #pragma unroll
            for (int mi = 0; mi < 2; ++mi)
                acc2[mi] = __builtin_amdgcn_mfma_f32_16x16x32_bf16(
                    af[mi][t], bv, acc2[mi], 0, 0, 0);
        }
        __builtin_amdgcn_s_setprio(0);
        // chunk 0 only: retire q0 (queue: q0:9, q1:9, D1:4 -> keep 13)
        if (c == 0) asm volatile("s_waitcnt vmcnt(13)" ::: "memory");

        // epilogue-2: bias + fp32 residual -> fp32 out (8 stores)
        {
            const int colg = c * 64 + wn2 * 16 + rl;
            const float bval = xq[c & 1][8];
            #pragma unroll
            for (int mi = 0; mi < 2; ++mi)
                #pragma unroll
                for (int i = 0; i < 4; ++i) {
                    const int rowl = wm2 * 32 + mi * 16 + quad * 4 + i;
                    ob[(size_t)rowl * 1024 + colg] =
                        acc2[mi][i] + bval + xq[c & 1][mi * 4 + i];
                }
        }
        if (c < 15) {
            // retire q(c+1)+D(c+1)+stores(c-1); keep stores(c):8
            asm volatile("s_waitcnt vmcnt(8)" ::: "memory");
            barx();
        }
    }
}

// ---------------------------------------------------------------------------
extern "C" void kernel_launch(void* const* d_in, const int* in_sizes, int n_in,
                              void* d_out, int out_size, void* d_ws, size_t ws_size,
                              hipStream_t stream) {
    const float* hidden = (const float*)d_in[0];   // (16, 2048, 1024) fp32
    const float* prob   = (const float*)d_in[1];   // (16, 8) fp32
    const float* w_down = (const float*)d_in[2];   // (8, 256, 1024) fp32
    const float* b_down = (const float*)d_in[3];   // (8, 256) fp32
    const float* w_up   = (const float*)d_in[4];   // (8, 1024, 256) fp32
    const float* b_up   = (const float*)d_in[5];   // (8, 1024) fp32
    float* out = (float*)d_out;                    // (16, 2048, 1024) fp32

    // workspace: merged weights (bf16) + biases (fp32), ~16.1 MB
    u16* Wd = (u16*)d_ws;                               // 16*256*1024 bf16
    u16* Wu = Wd + (size_t)16 * 256 * 1024;             // 16*1024*256 bf16
    float* bd = (float*)(Wu + (size_t)16 * 1024 * 256); // 16*256 f32
    float* bu = bd + 16 * 256;                          // 16*1024 f32

    merge_kernel<<<336, 256, 0, stream>>>(prob, w_down, b_down, w_up, b_up,
                                          Wd, Wu, bd, bu);

    fused_adapter<<<512, 512, 0, stream>>>(hidden, Wd, Wu, bd, bu, out);
}